// Round 6
// baseline (161.986 us; speedup 1.0000x reference)
//
#include <hip/hip_runtime.h>
#include <hip/hip_bf16.h>
#include <hip/hip_cooperative_groups.h>

namespace cg = cooperative_groups;

#define LN_EPS 1e-5f
#define BB 32        // batch
#define NI 200       // attended nodes
#define DD 64        // feature dim

typedef __attribute__((ext_vector_type(8))) short bf16x8;
typedef __attribute__((ext_vector_type(4))) short bf16x4;
typedef __attribute__((ext_vector_type(4))) float f32x4;

__device__ __forceinline__ float leaky(float x) { return fmaxf(x, 0.01f * x); }
__device__ __forceinline__ short f2bf(float x) {
  __hip_bfloat16 h = __float2bfloat16(x);
  return *reinterpret_cast<short*>(&h);
}
__device__ __forceinline__ float bf2fs(short s) {
  unsigned u = ((unsigned)(unsigned short)s) << 16;
  return __uint_as_float(u);
}

__device__ __forceinline__ void reduce2(float& a, float& b) {
#pragma unroll
  for (int m = 1; m < 64; m <<= 1) { a += __shfl_xor(a, m, 64); b += __shfl_xor(b, m, 64); }
}
__device__ __forceinline__ void reduce3(float& a, float& b, float& c) {
#pragma unroll
  for (int m = 1; m < 64; m <<= 1) {
    a += __shfl_xor(a, m, 64); b += __shfl_xor(b, m, 64); c += __shfl_xor(c, m, 64);
  }
}
__device__ __forceinline__ void rmax2(float& a, float& b) {
#pragma unroll
  for (int m = 1; m < 64; m <<= 1) {
    a = fmaxf(a, __shfl_xor(a, m, 64));
    b = fmaxf(b, __shfl_xor(b, m, 64));
  }
}

// ---------------- workspace layout (bytes) ----------------
// Per-b block (UA | UA2 | UAT | ST), staged contiguously by phase 3:
#define WB_STRIDE 88576
#define WB_UA2    26624
#define WB_UAT    53248
#define WB_ST     81920
#define WB_STAGE  86912          // bytes staged (UA..ST end; KV is LDS-local now)
// Extra (not staged):
#define WX_RAWD   2834432        // f32[BB][208][4] raw dots {p0,p1,p2,p3}
#define WX_TD     2940928        // f32[BB][2] raw iid*vi dots
#define WX_CR     2941184        // f32[BB][6] raw creds

// ---------------- LDS carve (bytes) ----------------
// [0,14336) = G region in phase 3; phase-1 scratch overlays it (dead by then):
//   sE0 @0 (4680) | sE1 @4680 (4680) | sV @9360 (1024) | sVi @10384 (512) | sLN @10896 (288)
#define L_G1    7168
#define L_SE0   0
#define L_SE1   4680
#define L_SV    9360
#define L_SVI   10384
#define L_SLN   10896
#define L_STAGE 14336
#define L_UA    14336
#define L_UA2   40960
#define L_UAT   67584
#define L_ST    96256
#define L_KV    101248           // written locally in phase 2 (not staged)
#define L_PART  102912           // phase 2: wmx[16]; phase 3: sPart
#define L_TOTAL 103936

// Single cooperative kernel, grid (7, BB) x 512.
// Phase 1 = old k1 (two 256-thread halves, i-tiles bx*2 / bx*2+1).
// grid.sync() ; Phase 2 = old k2 (skv local to LDS, ST rows sliced 30/block).
// grid.sync() ; Phase 3 = old k3 verbatim (stages UA..ST from ws, KV already local).
__global__ void __launch_bounds__(512, 1)
gat_coop(const float* __restrict__ emb,
         const float* __restrict__ lw,
         const float* __restrict__ lb,
         const float* __restrict__ W1,
         const float* __restrict__ W1b,
         const float* __restrict__ W2,
         const float* __restrict__ W2b,
         const float* __restrict__ a1,
         const float* __restrict__ a1b,
         const float* __restrict__ a2,
         const float* __restrict__ a2b,
         float* __restrict__ ws,
         float* __restrict__ out) {
  __shared__ __align__(16) char smem[L_TOTAL];
  float* sV   = (float*)(smem + L_SV);
  float* sVi  = (float*)(smem + L_SVI);
  short* sUA  = (short*)(smem + L_UA);
  short* sUA2 = (short*)(smem + L_UA2);
  short* sUAT = (short*)(smem + L_UAT);
  float* sST  = (float*)(smem + L_ST);
  float* sKV  = (float*)(smem + L_KV);
  float* sPart = (float*)(smem + L_PART);

  int b = blockIdx.y, bx = blockIdx.x, tid = threadIdx.x;
  int wv = tid >> 6, lane = tid & 63, q = lane >> 4, col = lane & 15;
  int th = tid >> 8, t2 = tid & 255;           // half index, thread-in-half

  char* wsb = (char*)ws + (size_t)b * WB_STRIDE;
  short* wUA  = (short*)wsb;
  short* wUA2 = (short*)(wsb + WB_UA2);
  short* wUAT = (short*)(wsb + WB_UAT);
  float* wST  = (float*)(wsb + WB_ST);
  float* wRAW = (float*)((char*)ws + WX_RAWD) + (size_t)b * 832;
  float* wTD  = (float*)((char*)ws + WX_TD) + b * 2;
  float* wCR  = (float*)((char*)ws + WX_CR) + b * 6;

  // ================= phase 1: LN + frags + raw dots (old k1) =================
  int it = bx * 2 + th;
  bool act1 = (it < 13);
  float* sE = (float*)(smem + (th ? L_SE1 : L_SE0));   // f32[18][65]
  float* sLN = (float*)(smem + L_SLN) + th * 36;

  if (act1) {
    for (int idx = t2; idx < 288; idx += 256) {
      int r = idx >> 4, qd = (idx & 15) << 2;
      int g = (r < 2) ? r : 2 + it * 16 + (r - 2);
      f32x4 v = {0, 0, 0, 0};
      if (g <= 201) v = *(const f32x4*)(emb + ((size_t)b * 202 + g) * 64 + qd);
      float* dst = sE + r * 65 + qd;
      dst[0] = v.x; dst[1] = v.y; dst[2] = v.z; dst[3] = v.w;
    }
  }
  // wave-specialized projections (waves 0-3 = half 0)
  if (wv == 0) {
    float p0 = 0, p1 = 0;
#pragma unroll 8
    for (int d = 0; d < 64; d++) {
      float x = W1[d * 64 + lane];
      p0 = fmaf(x, a1[d], p0); p1 = fmaf(x, a1[64 + d], p1);
    }
    sV[0 * 64 + lane] = p0; sV[1 * 64 + lane] = p1;
  } else if (wv == 1) {
    float p0 = 0, p1 = 0;
#pragma unroll 8
    for (int d = 0; d < 64; d++) {
      float x = W2[d * 64 + lane];
      p0 = fmaf(x, a2[d], p0); p1 = fmaf(x, a2[64 + d], p1);
    }
    sV[2 * 64 + lane] = p0; sV[3 * 64 + lane] = p1;
  } else if (wv == 2 && bx == 0) {
    float p = 0;
#pragma unroll 8
    for (int d = 0; d < 64; d++) p = fmaf(W1[d * 64 + lane], a1[128 + d], p);
    sVi[lane] = p;
    float c0 = W1b[lane] * a1[lane];
    float c1 = W1b[lane] * a1[64 + lane];
    float c2 = W1b[lane] * a1[128 + lane];
    reduce3(c0, c1, c2);
    if (lane == 0) { wCR[0] = c0; wCR[1] = c1; wCR[2] = c2; }
  } else if (wv == 3 && bx == 0) {
    float p = 0;
#pragma unroll 8
    for (int d = 0; d < 64; d++) p = fmaf(W2[d * 64 + lane], a2[128 + d], p);
    sVi[64 + lane] = p;
    float c3 = W2b[lane] * a2[lane];
    float c4 = W2b[lane] * a2[64 + lane];
    float c5 = W2b[lane] * a2[128 + lane];
    reduce3(c3, c4, c5);
    if (lane == 0) { wCR[3] = c3; wCR[4] = c4; wCR[5] = c5; }
  }
  __syncthreads();

  // LN stats: 8 threads/row (per half)
  {
    int o = t2 & 7, rr = t2 >> 3;
    float s = 0.f, s2 = 0.f;
    if (act1 && rr < 18) {
      const float* xr = sE + rr * 65 + o * 8;
#pragma unroll
      for (int k = 0; k < 8; k++) { float x = xr[k]; s += x; s2 = fmaf(x, x, s2); }
    }
#pragma unroll
    for (int m = 1; m < 8; m <<= 1) {
      s += __shfl_xor(s, m, 64); s2 += __shfl_xor(s2, m, 64);
    }
    if (act1 && rr < 18 && o == 0) {
      float mu = s * (1.f / 64);
      float var = fmaxf(s2 * (1.f / 64) - mu * mu, 0.f);
      sLN[rr * 2] = mu;
      sLN[rr * 2 + 1] = rsqrtf(var + LN_EPS);
    }
  }
  __syncthreads();

  // normalize in place (per half)
  if (act1) {
    int d = t2 & 63;
    float w = lw[d], bi = lb[d];
    for (int idx = t2; idx < 18 * 64; idx += 256) {
      int r = idx >> 6;
      float mu = sLN[r * 2], rinv = sLN[r * 2 + 1];
      float x = sE[r * 65 + d];
      sE[r * 65 + d] = (x - mu) * rinv * w + bi;
    }
  }
  __syncthreads();

  // out row 0 + raw t-dots (block bx==0, wave 2, uses half-0 sE)
  if (bx == 0 && wv == 2) {
    const float* sE0 = (const float*)(smem + L_SE0);
    float u0 = sE0[lane], iid = sE0[65 + lane];
    out[(size_t)(b * 201) * 64 + lane] = leaky(u0 * iid);
    float q0 = iid * sVi[lane], q1 = iid * sVi[64 + lane];
    reduce2(q0, q1);
    if (lane == 0) { wTD[0] = q0; wTD[1] = q1; }
  }
  // frag slices (per half)
  if (act1) {
    if (t2 < 128) {
      // node-major + squared frags for this i-tile
      int rem = t2, kh = rem >> 6, ln = rem & 63;
      int lnode = ln & 15, g = it * 16 + lnode;
      int dbase = kh * 32 + (ln >> 4) * 8, lr = 2 + lnode;
      bf16x8 pk, pk2;
      if (g < NI) {
        const float* yr = sE + lr * 65 + dbase;
#pragma unroll
        for (int k = 0; k < 8; k++) {
          float v = sE[dbase + k] * yr[k];
          short h = f2bf(v);
          pk[k] = h;
          float f = bf2fs(h);
          pk2[k] = f2bf(f * f);
        }
      } else {
#pragma unroll
        for (int k = 0; k < 8; k++) { pk[k] = 0; pk2[k] = 0; }
      }
      *(bf16x8*)(wUA + (it * 128 + rem) * 8) = pk;
      *(bf16x8*)(wUA2 + (it * 128 + rem) * 8) = pk2;
    } else {
      // d-major frag half-slice: p = it>>1, ir in {0,1}+2*(it&1)
      int tid2 = t2 - 128, d = tid2 & 63;
      int ir = (it & 1) * 2 + (tid2 >> 6), p = it >> 1;
      int i0 = p * 32 + ir * 8, ln0 = i0 - it * 16;   // 0 or 8
      float ud = sE[d];
      bf16x8 pk;
#pragma unroll
      for (int uu = 0; uu < 8; uu++) {
        int node = i0 + uu;
        pk[uu] = (node < NI) ? f2bf(ud * sE[(2 + ln0 + uu) * 65 + d]) : (short)0;
      }
      int off = ((p * 4 + (d >> 4)) * 64 + ((d & 15) + 16 * ir)) * 8;
      *(bf16x8*)(wUAT + off) = pk;
      if (it == 12) {
        // nodes 208..223 produced by no tile: zero-fill (poison guard)
        bf16x8 z;
#pragma unroll
        for (int uu = 0; uu < 8; uu++) z[uu] = 0;
        int off2 = ((p * 4 + (d >> 4)) * 64 + ((d & 15) + 16 * (ir + 2))) * 8;
        *(bf16x8*)(wUAT + off2) = z;
      }
    }
    // raw score dots: 8 threads/row, 16 rows
    if (t2 < 128) {
      int o = t2 & 7, rr = t2 >> 3;
      int i = it * 16 + rr;
      if (i < NI) {
        float uv0[8], uv1[8], uv2[8], uv3[8];
#pragma unroll
        for (int k = 0; k < 8; k++) {
          float u0k = sE[o * 8 + k];
          uv0[k] = u0k * sV[0 * 64 + o * 8 + k];
          uv1[k] = u0k * sV[1 * 64 + o * 8 + k];
          uv2[k] = u0k * sV[2 * 64 + o * 8 + k];
          uv3[k] = u0k * sV[3 * 64 + o * 8 + k];
        }
        const float* yr = sE + (2 + rr) * 65 + o * 8;
        float p0 = 0, p1 = 0, p2 = 0, p3 = 0;
#pragma unroll
        for (int k = 0; k < 8; k++) {
          float y = yr[k];
          p0 = fmaf(y, uv0[k], p0); p1 = fmaf(y, uv1[k], p1);
          p2 = fmaf(y, uv2[k], p2); p3 = fmaf(y, uv3[k], p3);
        }
#pragma unroll
        for (int m = 1; m < 8; m <<= 1) {
          p0 += __shfl_xor(p0, m, 64); p1 += __shfl_xor(p1, m, 64);
          p2 += __shfl_xor(p2, m, 64); p3 += __shfl_xor(p3, m, 64);
        }
        if (o == 0) {
          wRAW[i * 4 + 0] = p0; wRAW[i * 4 + 1] = p1;
          wRAW[i * 4 + 2] = p2; wRAW[i * 4 + 3] = p3;
        }
      }
    }
  }

  cg::this_grid().sync();

  // ================= phase 2: softmax stats (old k2) =================
  {
    float c0 = wCR[0], c1 = wCR[1], c2 = wCR[2];
    float c3 = wCR[3], c4 = wCR[4], c5 = wCR[5];
    float t1 = (wTD[0] + c2) + a1b[0];
    float t2h = (wTD[1] + c5) + a2b[0];

    if (tid < 208) {
      float s1 = 0.f, s2 = 0.f;
      if (tid < NI) {
        s1 = wRAW[tid * 4 + 1] + c1;
        s2 = wRAW[tid * 4 + 3] + c4;
      }
      sKV[tid] = s1; sKV[208 + tid] = s2;
    }
    __syncthreads();

    // block max of sk over real j
    float* wmx = sPart;    // 16 floats, dead before phase-A writes sPart
    {
      float m1 = (tid < NI) ? sKV[tid] : -3e38f;
      float m2 = (tid < NI) ? sKV[208 + tid] : -3e38f;
      rmax2(m1, m2);
      if (lane == 0) { wmx[wv * 2] = m1; wmx[wv * 2 + 1] = m2; }
    }
    __syncthreads();

    // stats: 4 threads per (row, head); this block covers rows [bx*30, bx*30+30)
    {
      int o = tid & 3, item = tid >> 2;
      int rl = item >> 1, sh = item & 1;
      if (rl < 30) {
        int r = bx * 30 + rl;
        if (r < 208) {
          float* st = wST + r * 6 + sh * 3;
          if (r < NI) {
            float mx = -3e38f;
#pragma unroll
            for (int k = 0; k < 8; k++) mx = fmaxf(mx, wmx[k * 2 + sh]);
            float base = (wRAW[r * 4 + (sh ? 2 : 0)] + (sh ? c3 : c0)) + (sh ? t2h : t1);
            float rm = leaky(base + mx);
            const float* skh = sKV + sh * 208;
            float den = 0.f;
            int j0 = o * 50;
#pragma unroll 5
            for (int j = j0; j < j0 + 50; j++) {
              float s = base + skh[j];
              den += __expf(fmaxf(s, 0.01f * s) - rm);
            }
            den += __shfl_xor(den, 1, 64);
            den += __shfl_xor(den, 2, 64);
            if (o == 0) { st[0] = base; st[1] = rm; st[2] = 1.0f / den; }
          } else if (o == 0) {
            st[0] = 0.f; st[1] = 0.f; st[2] = 0.f;
          }
        }
      }
    }
  }

  cg::this_grid().sync();

  // ================= phase 3: MFMA phases (old k3) =================
  // stage UA..ST (86912 B) from ws; sKV already resident in LDS
  {
    const f32x4* src = (const f32x4*)wsb;
    f32x4* dst = (f32x4*)(smem + L_STAGE);
    for (int idx = tid; idx < WB_STAGE / 16; idx += 512) dst[idx] = src[idx];
  }
  // zero G k-tails (i = 208..223)
  short* sG0 = (short*)smem;
  short* sG1 = (short*)(smem + L_G1);
  if (tid < 128) ((int*)sG0)[1664 + tid] = 0;
  else if (tid < 256) ((int*)sG1)[1664 + (tid - 128)] = 0;
  __syncthreads();

  // ---- phase A: S/T MFMAs + epilogue -> G (half owns j-tile bx*2+half) ----
  int half = wv >> 2, wq = wv & 3;
  int jt = bx * 2 + half;
  bool act = (jt < 13);
  short* sGh = half ? sG1 : sG0;
  float* sPh = sPart + half * 128;    // [4 wq][2][16]

  if (act) {
    bf16x8 bf0 = *(bf16x8*)(sUA + ((jt * 2 + 0) * 64 + lane) * 8);
    bf16x8 bf1 = *(bf16x8*)(sUA + ((jt * 2 + 1) * 64 + lane) * 8);
    bf16x8 b2f0 = *(bf16x8*)(sUA2 + ((jt * 2 + 0) * 64 + lane) * 8);
    bf16x8 b2f1 = *(bf16x8*)(sUA2 + ((jt * 2 + 1) * 64 + lane) * 8);
    int jglob = jt * 16 + col;
    float skj1 = sKV[jglob], skj2 = sKV[208 + jglob];
    float mpart = 0.f, spart = 0.f;
    for (int it2 = wq; it2 < 13; it2 += 4) {
      bf16x8 af0 = *(bf16x8*)(sUA + ((it2 * 2 + 0) * 64 + lane) * 8);
      bf16x8 af1 = *(bf16x8*)(sUA + ((it2 * 2 + 1) * 64 + lane) * 8);
      bf16x8 a2f0 = *(bf16x8*)(sUA2 + ((it2 * 2 + 0) * 64 + lane) * 8);
      bf16x8 a2f1 = *(bf16x8*)(sUA2 + ((it2 * 2 + 1) * 64 + lane) * 8);
      f32x4 s = {0, 0, 0, 0}, t = {0, 0, 0, 0};
      s = __builtin_amdgcn_mfma_f32_16x16x32_bf16(af0, bf0, s, 0, 0, 0);
      s = __builtin_amdgcn_mfma_f32_16x16x32_bf16(af1, bf1, s, 0, 0, 0);
      t = __builtin_amdgcn_mfma_f32_16x16x32_bf16(a2f0, b2f0, t, 0, 0, 0);
      t = __builtin_amdgcn_mfma_f32_16x16x32_bf16(a2f1, b2f1, t, 0, 0, 0);
      bf16x4 gp;
#pragma unroll
      for (int r = 0; r < 4; r++) {
        int i = it2 * 16 + q * 4 + r;
        const float* st = sST + i * 6;
        float mu = s[r] * (1.f / 64);
        float var = fmaxf(t[r] * (1.f / 64) - mu * mu, 0.f);
        float inv = rsqrtf(var + LN_EPS);
        float sc1 = st[0] + skj1;
        float e1 = __expf(fmaxf(sc1, 0.01f * sc1) - st[1]) * st[2];
        float sc2 = st[3] + skj2;
        float e2 = __expf(fmaxf(sc2, 0.01f * sc2) - st[4]) * st[5];
        float c = 0.5f * (e1 + e2);
        float g = c * inv;
        mpart = fmaf(g, mu, mpart);
        spart += c;
        gp[r] = f2bf(g);
      }
      int kl = (it2 & 1) * 16 + q * 4;
      int off = ((it2 >> 1) * 64 + (col + 16 * (kl >> 3))) * 8 + (kl & 7);
      *(bf16x4*)(sGh + off) = gp;
    }
    mpart += __shfl_xor(mpart, 16, 64); mpart += __shfl_xor(mpart, 32, 64);
    spart += __shfl_xor(spart, 16, 64); spart += __shfl_xor(spart, 32, 64);
    if (lane < 16) {
      sPh[(wq * 2 + 0) * 16 + lane] = mpart;
      sPh[(wq * 2 + 1) * 16 + lane] = spart;
    }
  }
  __syncthreads();

  // ---- phase B: H = G^T * UA + output epilogue ----
  if (act) {
    f32x4 acc = {0, 0, 0, 0};
#pragma unroll
    for (int kt = 0; kt < 7; kt++) {
      bf16x8 ga = *(bf16x8*)(sGh + (kt * 64 + lane) * 8);
      bf16x8 ub = *(bf16x8*)(sUAT + ((kt * 4 + wq) * 64 + lane) * 8);
      acc = __builtin_amdgcn_mfma_f32_16x16x32_bf16(ga, ub, acc, 0, 0, 0);
    }
    int d = wq * 16 + col;
    float w = lw[d], bia = lb[d];
#pragma unroll
    for (int r = 0; r < 4; r++) {
      int jl = q * 4 + r, jg = jt * 16 + jl;
      if (jg < NI) {
        float m = sPh[0 * 16 + jl] + sPh[2 * 16 + jl] +
                  sPh[4 * 16 + jl] + sPh[6 * 16 + jl];
        float S = sPh[1 * 16 + jl] + sPh[3 * 16 + jl] +
                  sPh[5 * 16 + jl] + sPh[7 * 16 + jl];
        int cn = jt * 128 + (d >> 5) * 64 + ((d >> 3) & 3) * 16 + (jg & 15);
        float uajd = bf2fs(sUA[cn * 8 + (d & 7)]);
        float att = w * (uajd * acc[r] - m) + bia * S;
        out[(size_t)(b * 201 + 1 + jg) * 64 + d] = leaky(att);
      }
    }
  }
}

extern "C" void kernel_launch(void* const* d_in, const int* in_sizes, int n_in,
                              void* d_out, int out_size, void* d_ws, size_t ws_size,
                              hipStream_t stream) {
  const float* emb = (const float*)d_in[0];
  const float* lw  = (const float*)d_in[1];
  const float* lb  = (const float*)d_in[2];
  const float* W1  = (const float*)d_in[3];
  const float* W1b = (const float*)d_in[4];
  const float* W2  = (const float*)d_in[5];
  const float* W2b = (const float*)d_in[6];
  const float* a1  = (const float*)d_in[7];
  const float* a1b = (const float*)d_in[8];
  const float* a2  = (const float*)d_in[9];
  const float* a2b = (const float*)d_in[10];
  float* ws = (float*)d_ws;
  float* out = (float*)d_out;

  void* args[] = {(void*)&emb, (void*)&lw, (void*)&lb, (void*)&W1, (void*)&W1b,
                  (void*)&W2, (void*)&W2b, (void*)&a1, (void*)&a1b, (void*)&a2,
                  (void*)&a2b, (void*)&ws, (void*)&out};
  hipLaunchCooperativeKernel((const void*)gat_coop, dim3(7, BB), dim3(512),
                             args, 0, stream);
}

// Round 7
// 94.453 us; speedup vs baseline: 1.7150x; 1.7150x over previous
//
#include <hip/hip_runtime.h>
#include <hip/hip_bf16.h>

#define LN_EPS 1e-5f
#define BB 32        // batch
#define NI 200       // attended nodes
#define DD 64        // feature dim

typedef __attribute__((ext_vector_type(8))) short bf16x8;
typedef __attribute__((ext_vector_type(4))) short bf16x4;
typedef __attribute__((ext_vector_type(4))) float f32x4;

__device__ __forceinline__ float leaky(float x) { return fmaxf(x, 0.01f * x); }
__device__ __forceinline__ short f2bf(float x) {
  __hip_bfloat16 h = __float2bfloat16(x);
  return *reinterpret_cast<short*>(&h);
}
__device__ __forceinline__ float bf2fs(short s) {
  unsigned u = ((unsigned)(unsigned short)s) << 16;
  return __uint_as_float(u);
}

__device__ __forceinline__ void reduce2(float& a, float& b) {
#pragma unroll
  for (int m = 1; m < 64; m <<= 1) { a += __shfl_xor(a, m, 64); b += __shfl_xor(b, m, 64); }
}
__device__ __forceinline__ void reduce3(float& a, float& b, float& c) {
#pragma unroll
  for (int m = 1; m < 64; m <<= 1) {
    a += __shfl_xor(a, m, 64); b += __shfl_xor(b, m, 64); c += __shfl_xor(c, m, 64);
  }
}
__device__ __forceinline__ void rmax2(float& a, float& b) {
#pragma unroll
  for (int m = 1; m < 64; m <<= 1) {
    a = fmaxf(a, __shfl_xor(a, m, 64));
    b = fmaxf(b, __shfl_xor(b, m, 64));
  }
}

// ---------------- workspace layout (bytes) ----------------
// Per-b staged block (order MUST match k23's LDS stage region):
//   UA (26624) | UA2 (26624) | UAT (28672)  = 81920
#define WB_STRIDE 81920
#define WB_UA2    26624
#define WB_UAT    53248
// Extra (not staged):
#define WX_RAWD   2621440        // f32[BB][208][4] raw dots {p0,p1,p2,p3}
#define WX_TD     2727936        // f32[BB][2] raw iid*vi dots
#define WX_CR     2728192        // f32[BB][6] raw creds

// ============ k1: per-(i-tile, b) LN + frags + raw dots ============
__global__ void __launch_bounds__(256)
gat_k1(const float* __restrict__ emb,
       const float* __restrict__ lw,
       const float* __restrict__ lb,
       const float* __restrict__ W1,
       const float* __restrict__ W1b,
       const float* __restrict__ W2,
       const float* __restrict__ W2b,
       const float* __restrict__ a1,
       const float* __restrict__ a2,
       float* __restrict__ ws,
       float* __restrict__ out) {
  __shared__ float sE[18 * 65];   // rows: 0,1 = u,iid; 2..17 = nodes it*16..+15
  __shared__ float sV[4 * 64];    // v1q,v1k,v2q,v2k
  __shared__ float sVi[2 * 64];   // vi1, vi2 (it==0 only)
  __shared__ float sLN[18 * 2];

  int b = blockIdx.y, it = blockIdx.x, tid = threadIdx.x;
  int wv = tid >> 6, lane = tid & 63;

  char* wsb = (char*)ws + (size_t)b * WB_STRIDE;
  short* wUA  = (short*)wsb;
  short* wUA2 = (short*)(wsb + WB_UA2);
  short* wUAT = (short*)(wsb + WB_UAT);
  float* wRAW = (float*)((char*)ws + WX_RAWD) + (size_t)b * 832;
  float* wTD  = (float*)((char*)ws + WX_TD) + b * 2;
  float* wCR  = (float*)((char*)ws + WX_CR) + b * 6;

  // stage 18 rows of raw emb (zeros for nonexistent rows)
  for (int idx = tid; idx < 288; idx += 256) {
    int r = idx >> 4, qd = (idx & 15) << 2;
    int g = (r < 2) ? r : 2 + it * 16 + (r - 2);
    f32x4 v = {0, 0, 0, 0};
    if (g <= 201) v = *(const f32x4*)(emb + ((size_t)b * 202 + g) * 64 + qd);
    float* dst = sE + r * 65 + qd;
    dst[0] = v.x; dst[1] = v.y; dst[2] = v.z; dst[3] = v.w;
  }
  // wave-specialized projections
  if (wv == 0) {
    float p0 = 0, p1 = 0;
#pragma unroll 8
    for (int d = 0; d < 64; d++) {
      float x = W1[d * 64 + lane];
      p0 = fmaf(x, a1[d], p0); p1 = fmaf(x, a1[64 + d], p1);
    }
    sV[0 * 64 + lane] = p0; sV[1 * 64 + lane] = p1;
  } else if (wv == 1) {
    float p0 = 0, p1 = 0;
#pragma unroll 8
    for (int d = 0; d < 64; d++) {
      float x = W2[d * 64 + lane];
      p0 = fmaf(x, a2[d], p0); p1 = fmaf(x, a2[64 + d], p1);
    }
    sV[2 * 64 + lane] = p0; sV[3 * 64 + lane] = p1;
  } else if (wv == 2 && it == 0) {
    float p = 0;
#pragma unroll 8
    for (int d = 0; d < 64; d++) p = fmaf(W1[d * 64 + lane], a1[128 + d], p);
    sVi[lane] = p;
    float c0 = W1b[lane] * a1[lane];
    float c1 = W1b[lane] * a1[64 + lane];
    float c2 = W1b[lane] * a1[128 + lane];
    reduce3(c0, c1, c2);
    if (lane == 0) { wCR[0] = c0; wCR[1] = c1; wCR[2] = c2; }
  } else if (wv == 3 && it == 0) {
    float p = 0;
#pragma unroll 8
    for (int d = 0; d < 64; d++) p = fmaf(W2[d * 64 + lane], a2[128 + d], p);
    sVi[64 + lane] = p;
    float c3 = W2b[lane] * a2[lane];
    float c4 = W2b[lane] * a2[64 + lane];
    float c5 = W2b[lane] * a2[128 + lane];
    reduce3(c3, c4, c5);
    if (lane == 0) { wCR[3] = c3; wCR[4] = c4; wCR[5] = c5; }
  }
  __syncthreads();

  // LN stats: 8 threads/row
  {
    int o = tid & 7, rr = tid >> 3;
    float s = 0.f, s2 = 0.f;
    if (rr < 18) {
      const float* xr = sE + rr * 65 + o * 8;
#pragma unroll
      for (int k = 0; k < 8; k++) { float x = xr[k]; s += x; s2 = fmaf(x, x, s2); }
    }
#pragma unroll
    for (int m = 1; m < 8; m <<= 1) {
      s += __shfl_xor(s, m, 64); s2 += __shfl_xor(s2, m, 64);
    }
    if (rr < 18 && o == 0) {
      float mu = s * (1.f / 64);
      float var = fmaxf(s2 * (1.f / 64) - mu * mu, 0.f);
      sLN[rr * 2] = mu;
      sLN[rr * 2 + 1] = rsqrtf(var + LN_EPS);
    }
  }
  __syncthreads();

  // normalize in place
  {
    int d = tid & 63;
    float w = lw[d], bi = lb[d];
    for (int idx = tid; idx < 18 * 64; idx += 256) {
      int r = idx >> 6;
      float mu = sLN[r * 2], rinv = sLN[r * 2 + 1];
      float x = sE[r * 65 + d];
      sE[r * 65 + d] = (x - mu) * rinv * w + bi;
    }
  }
  __syncthreads();

  // out row 0 + raw t-dots (block it==0)
  if (it == 0 && wv == 2) {
    float u0 = sE[lane], iid = sE[65 + lane];
    out[(size_t)(b * 201) * 64 + lane] = leaky(u0 * iid);
    float q0 = iid * sVi[lane], q1 = iid * sVi[64 + lane];
    reduce2(q0, q1);
    if (lane == 0) { wTD[0] = q0; wTD[1] = q1; }
  }
  // frag slices
  if (tid < 128) {
    // node-major + squared frags for this i-tile
    int rem = tid, kh = rem >> 6, ln = rem & 63;
    int lnode = ln & 15, g = it * 16 + lnode;
    int dbase = kh * 32 + (ln >> 4) * 8, lr = 2 + lnode;
    bf16x8 pk, pk2;
    if (g < NI) {
      const float* yr = sE + lr * 65 + dbase;
#pragma unroll
      for (int k = 0; k < 8; k++) {
        float v = sE[dbase + k] * yr[k];
        short h = f2bf(v);
        pk[k] = h;
        float f = bf2fs(h);
        pk2[k] = f2bf(f * f);
      }
    } else {
#pragma unroll
      for (int k = 0; k < 8; k++) { pk[k] = 0; pk2[k] = 0; }
    }
    *(bf16x8*)(wUA + (it * 128 + rem) * 8) = pk;
    *(bf16x8*)(wUA2 + (it * 128 + rem) * 8) = pk2;
  } else {
    // d-major frag half-slice: p = it>>1, ir in {0,1}+2*(it&1)
    int tid2 = tid - 128, d = tid2 & 63;
    int ir = (it & 1) * 2 + (tid2 >> 6), p = it >> 1;
    int i0 = p * 32 + ir * 8, ln0 = i0 - it * 16;   // 0 or 8
    float ud = sE[d];
    bf16x8 pk;
#pragma unroll
    for (int uu = 0; uu < 8; uu++) {
      int node = i0 + uu;
      pk[uu] = (node < NI) ? f2bf(ud * sE[(2 + ln0 + uu) * 65 + d]) : (short)0;
    }
    int off = ((p * 4 + (d >> 4)) * 64 + ((d & 15) + 16 * ir)) * 8;
    *(bf16x8*)(wUAT + off) = pk;
    if (it == 12) {
      // nodes 208..223 produced by no tile: zero-fill (poison guard)
      bf16x8 z;
#pragma unroll
      for (int uu = 0; uu < 8; uu++) z[uu] = 0;
      int off2 = ((p * 4 + (d >> 4)) * 64 + ((d & 15) + 16 * (ir + 2))) * 8;
      *(bf16x8*)(wUAT + off2) = z;
    }
  }
  // raw score dots: 8 threads/row, 16 rows
  if (tid < 128) {
    int o = tid & 7, rr = tid >> 3;
    int i = it * 16 + rr;
    if (i < NI) {
      float uv0[8], uv1[8], uv2[8], uv3[8];
#pragma unroll
      for (int k = 0; k < 8; k++) {
        float u0k = sE[o * 8 + k];
        uv0[k] = u0k * sV[0 * 64 + o * 8 + k];
        uv1[k] = u0k * sV[1 * 64 + o * 8 + k];
        uv2[k] = u0k * sV[2 * 64 + o * 8 + k];
        uv3[k] = u0k * sV[3 * 64 + o * 8 + k];
      }
      const float* yr = sE + (2 + rr) * 65 + o * 8;
      float p0 = 0, p1 = 0, p2 = 0, p3 = 0;
#pragma unroll
      for (int k = 0; k < 8; k++) {
        float y = yr[k];
        p0 = fmaf(y, uv0[k], p0); p1 = fmaf(y, uv1[k], p1);
        p2 = fmaf(y, uv2[k], p2); p3 = fmaf(y, uv3[k], p3);
      }
#pragma unroll
      for (int m = 1; m < 8; m <<= 1) {
        p0 += __shfl_xor(p0, m, 64); p1 += __shfl_xor(p1, m, 64);
        p2 += __shfl_xor(p2, m, 64); p3 += __shfl_xor(p3, m, 64);
      }
      if (o == 0) {
        wRAW[i * 4 + 0] = p0; wRAW[i * 4 + 1] = p1;
        wRAW[i * 4 + 2] = p2; wRAW[i * 4 + 3] = p3;
      }
    }
  }
}

// ============ k23: softmax stats (local) + MFMA phases ============
// LDS: G (2 x 7168) | staged UA|UA2|UAT (81920) | sST (4992) | sKV (1664) | sPart (1024)
#define L_G1    7168
#define L_STAGE 14336
#define L_UA    14336
#define L_UA2   40960
#define L_UAT   67584
#define L_ST    96256
#define L_KV    101248
#define L_PART  102912           // stats phase: wmx[16]; MFMA phase: sPart
#define L_TOTAL 103936

__global__ void __launch_bounds__(512, 1)
gat_k23(const float* __restrict__ ws,
        const float* __restrict__ lw,
        const float* __restrict__ lb,
        const float* __restrict__ a1b,
        const float* __restrict__ a2b,
        float* __restrict__ out) {
  __shared__ __align__(16) char smem[L_TOTAL];
  short* sUA  = (short*)(smem + L_UA);
  short* sUA2 = (short*)(smem + L_UA2);
  short* sUAT = (short*)(smem + L_UAT);
  float* sST  = (float*)(smem + L_ST);
  float* sKV  = (float*)(smem + L_KV);
  float* sPart = (float*)(smem + L_PART);

  int b = blockIdx.y, bx = blockIdx.x, tid = threadIdx.x;
  int wv = tid >> 6, lane = tid & 63, q = lane >> 4, col = lane & 15;

  const char* wsb = (const char*)ws + (size_t)b * WB_STRIDE;
  const float* wRAW = (const float*)((const char*)ws + WX_RAWD) + (size_t)b * 832;
  const float* wTD  = (const float*)((const char*)ws + WX_TD) + b * 2;
  const float* wCR  = (const float*)((const char*)ws + WX_CR) + b * 6;

  // linear stage of UA|UA2|UAT (L2-hot after first block per b)
  {
    const f32x4* src = (const f32x4*)wsb;
    f32x4* dst = (f32x4*)(smem + L_STAGE);
    for (int idx = tid; idx < WB_STRIDE / 16; idx += 512) dst[idx] = src[idx];
  }
  float c0 = wCR[0], c1 = wCR[1], c2 = wCR[2];
  float c3 = wCR[3], c4 = wCR[4], c5 = wCR[5];
  float t1 = (wTD[0] + c2) + a1b[0];
  float t2 = (wTD[1] + c5) + a2b[0];

  if (tid < 208) {
    float s1 = 0.f, s2 = 0.f;
    if (tid < NI) {
      s1 = wRAW[tid * 4 + 1] + c1;
      s2 = wRAW[tid * 4 + 3] + c4;
    }
    sKV[tid] = s1; sKV[208 + tid] = s2;
  }
  // pad rows 200..207: zero stats (-> g=0)
  if (tid < 48) sST[1200 + tid] = 0.f;
  __syncthreads();

  // block max of sk over real j (wmx overlays sPart; dead before phase A)
  float* wmx = sPart;
  {
    float m1 = (tid < NI) ? sKV[tid] : -3e38f;
    float m2 = (tid < NI) ? sKV[208 + tid] : -3e38f;
    rmax2(m1, m2);
    if (lane == 0) { wmx[wv * 2] = m1; wmx[wv * 2 + 1] = m2; }
  }
  __syncthreads();

  // softmax stats: 1 thread per (row, head) — R3-verified pattern
  {
    int sh = -1, si = 0;
    if (tid < NI) { sh = 0; si = tid; }
    else if (tid >= 256 && tid < 256 + NI) { sh = 1; si = tid - 256; }
    if (sh >= 0) {
      float mx = -3e38f;
#pragma unroll
      for (int k = 0; k < 8; k++) mx = fmaxf(mx, wmx[k * 2 + sh]);
      float base = (wRAW[si * 4 + (sh ? 2 : 0)] + (sh ? c3 : c0)) + (sh ? t2 : t1);
      float rm = leaky(base + mx);               // leaky monotone
      const float* skh = sKV + sh * 208;
      float d0 = 0, d1 = 0, d2 = 0, d3 = 0;
      for (int j = 0; j < NI; j += 4) {
        float s0 = base + skh[j + 0]; d0 += __expf(fmaxf(s0, 0.01f * s0) - rm);
        float s1 = base + skh[j + 1]; d1 += __expf(fmaxf(s1, 0.01f * s1) - rm);
        float s2 = base + skh[j + 2]; d2 += __expf(fmaxf(s2, 0.01f * s2) - rm);
        float s3 = base + skh[j + 3]; d3 += __expf(fmaxf(s3, 0.01f * s3) - rm);
      }
      float* st = sST + si * 6 + sh * 3;
      st[0] = base;
      st[1] = rm;
      st[2] = 1.0f / ((d0 + d1) + (d2 + d3));
    }
  }
  // zero G k-tails (i = 208..223)
  short* sG0 = (short*)smem;
  short* sG1 = (short*)(smem + L_G1);
  if (tid < 128) ((int*)sG0)[1664 + tid] = 0;
  else if (tid < 256) ((int*)sG1)[1664 + (tid - 128)] = 0;
  __syncthreads();

  // ---- phase A: S/T MFMAs + epilogue -> G (half owns j-tile bx*2+half) ----
  int half = wv >> 2, wq = wv & 3;
  int jt = bx * 2 + half;
  bool act = (jt < 13);
  short* sGh = half ? sG1 : sG0;
  float* sPh = sPart + half * 128;    // [4 wq][2][16]

  if (act) {
    bf16x8 bf0 = *(bf16x8*)(sUA + ((jt * 2 + 0) * 64 + lane) * 8);
    bf16x8 bf1 = *(bf16x8*)(sUA + ((jt * 2 + 1) * 64 + lane) * 8);
    bf16x8 b2f0 = *(bf16x8*)(sUA2 + ((jt * 2 + 0) * 64 + lane) * 8);
    bf16x8 b2f1 = *(bf16x8*)(sUA2 + ((jt * 2 + 1) * 64 + lane) * 8);
    int jglob = jt * 16 + col;
    float skj1 = sKV[jglob], skj2 = sKV[208 + jglob];
    float mpart = 0.f, spart = 0.f;
    for (int it = wq; it < 13; it += 4) {
      bf16x8 af0 = *(bf16x8*)(sUA + ((it * 2 + 0) * 64 + lane) * 8);
      bf16x8 af1 = *(bf16x8*)(sUA + ((it * 2 + 1) * 64 + lane) * 8);
      bf16x8 a2f0 = *(bf16x8*)(sUA2 + ((it * 2 + 0) * 64 + lane) * 8);
      bf16x8 a2f1 = *(bf16x8*)(sUA2 + ((it * 2 + 1) * 64 + lane) * 8);
      f32x4 s = {0, 0, 0, 0}, t = {0, 0, 0, 0};
      s = __builtin_amdgcn_mfma_f32_16x16x32_bf16(af0, bf0, s, 0, 0, 0);
      s = __builtin_amdgcn_mfma_f32_16x16x32_bf16(af1, bf1, s, 0, 0, 0);
      t = __builtin_amdgcn_mfma_f32_16x16x32_bf16(a2f0, b2f0, t, 0, 0, 0);
      t = __builtin_amdgcn_mfma_f32_16x16x32_bf16(a2f1, b2f1, t, 0, 0, 0);
      bf16x4 gp;
#pragma unroll
      for (int r = 0; r < 4; r++) {
        int i = it * 16 + q * 4 + r;
        const float* st = sST + i * 6;
        float mu = s[r] * (1.f / 64);
        float var = fmaxf(t[r] * (1.f / 64) - mu * mu, 0.f);
        float inv = rsqrtf(var + LN_EPS);
        float sc1 = st[0] + skj1;
        float e1 = __expf(fmaxf(sc1, 0.01f * sc1) - st[1]) * st[2];
        float sc2 = st[3] + skj2;
        float e2 = __expf(fmaxf(sc2, 0.01f * sc2) - st[4]) * st[5];
        float c = 0.5f * (e1 + e2);
        float g = c * inv;
        mpart = fmaf(g, mu, mpart);
        spart += c;
        gp[r] = f2bf(g);
      }
      int kl = (it & 1) * 16 + q * 4;
      int off = ((it >> 1) * 64 + (col + 16 * (kl >> 3))) * 8 + (kl & 7);
      *(bf16x4*)(sGh + off) = gp;
    }
    mpart += __shfl_xor(mpart, 16, 64); mpart += __shfl_xor(mpart, 32, 64);
    spart += __shfl_xor(spart, 16, 64); spart += __shfl_xor(spart, 32, 64);
    if (lane < 16) {
      sPh[(wq * 2 + 0) * 16 + lane] = mpart;
      sPh[(wq * 2 + 1) * 16 + lane] = spart;
    }
  }
  __syncthreads();

  // ---- phase B: H = G^T * UA + output epilogue ----
  if (act) {
    f32x4 acc = {0, 0, 0, 0};
#pragma unroll
    for (int kt = 0; kt < 7; kt++) {
      bf16x8 ga = *(bf16x8*)(sGh + (kt * 64 + lane) * 8);
      bf16x8 ub = *(bf16x8*)(sUAT + ((kt * 4 + wq) * 64 + lane) * 8);
      acc = __builtin_amdgcn_mfma_f32_16x16x32_bf16(ga, ub, acc, 0, 0, 0);
    }
    int d = wq * 16 + col;
    float w = lw[d], bia = lb[d];
#pragma unroll
    for (int r = 0; r < 4; r++) {
      int jl = q * 4 + r, jg = jt * 16 + jl;
      if (jg < NI) {
        float m = sPh[0 * 16 + jl] + sPh[2 * 16 + jl] +
                  sPh[4 * 16 + jl] + sPh[6 * 16 + jl];
        float S = sPh[1 * 16 + jl] + sPh[3 * 16 + jl] +
                  sPh[5 * 16 + jl] + sPh[7 * 16 + jl];
        int cn = jt * 128 + (d >> 5) * 64 + ((d >> 3) & 3) * 16 + (jg & 15);
        float uajd = bf2fs(sUA[cn * 8 + (d & 7)]);
        float att = w * (uajd * acc[r] - m) + bia * S;
        out[(size_t)(b * 201 + 1 + jg) * 64 + d] = leaky(att);
      }
    }
  }
}

extern "C" void kernel_launch(void* const* d_in, const int* in_sizes, int n_in,
                              void* d_out, int out_size, void* d_ws, size_t ws_size,
                              hipStream_t stream) {
  const float* emb = (const float*)d_in[0];
  const float* lw  = (const float*)d_in[1];
  const float* lb  = (const float*)d_in[2];
  const float* W1  = (const float*)d_in[3];
  const float* W1b = (const float*)d_in[4];
  const float* W2  = (const float*)d_in[5];
  const float* W2b = (const float*)d_in[6];
  const float* a1  = (const float*)d_in[7];
  const float* a1b = (const float*)d_in[8];
  const float* a2  = (const float*)d_in[9];
  const float* a2b = (const float*)d_in[10];
  float* ws = (float*)d_ws;
  float* out = (float*)d_out;

  gat_k1<<<dim3(13, BB), dim3(256), 0, stream>>>(emb, lw, lb, W1, W1b, W2, W2b,
                                                 a1, a2, ws, out);
  gat_k23<<<dim3(7, BB), dim3(512), 0, stream>>>(ws, lw, lb, a1b, a2b, out);
}